// Round 18
// baseline (1667.388 us; speedup 1.0000x reference)
//
#include <hip/hip_runtime.h>
#include <hip/hip_fp16.h>

#define B_  16
#define T_  400
#define F_  512
#define U_  1024
#define G4_ 4096

typedef __attribute__((ext_vector_type(8))) short short8;
typedef __attribute__((ext_vector_type(4))) float f32x4;

__device__ __forceinline__ unsigned bf16bits(float f) {
  unsigned u = __float_as_uint(f);
  return (u + 0x7fffu + ((u >> 16) & 1u)) >> 16;   // RNE f32->bf16
}
__device__ __forceinline__ float sigm(float x)   { return 1.f/(1.f + __expf(-x)); }
__device__ __forceinline__ float tanh_f(float x) { return 2.f/(1.f + __expf(-2.f*x)) - 1.f; }

__device__ __forceinline__ void ast(unsigned* p, unsigned v) {
  __hip_atomic_store(p, v, __ATOMIC_RELAXED, __HIP_MEMORY_SCOPE_AGENT);
}

// HARDENED coherent load (rule #18-safe): waitcnt fused with the loads,
// early-clobber outputs -> tag checks provably post-wait.
__device__ __forceinline__ void load_frag8(const unsigned* p,
    uint4& q0, uint4& q1, uint4& q2, uint4& q3,
    uint4& q4, uint4& q5, uint4& q6, uint4& q7) {
  asm volatile(
    "global_load_dwordx4 %0, %[a], off sc0 sc1\n\t"
    "global_load_dwordx4 %1, %[a], off offset:64 sc0 sc1\n\t"
    "global_load_dwordx4 %2, %[a], off offset:128 sc0 sc1\n\t"
    "global_load_dwordx4 %3, %[a], off offset:192 sc0 sc1\n\t"
    "global_load_dwordx4 %4, %[a], off offset:256 sc0 sc1\n\t"
    "global_load_dwordx4 %5, %[a], off offset:320 sc0 sc1\n\t"
    "global_load_dwordx4 %6, %[a], off offset:384 sc0 sc1\n\t"
    "global_load_dwordx4 %7, %[a], off offset:448 sc0 sc1\n\t"
    "s_waitcnt vmcnt(0)"
    : "=&v"(q0), "=&v"(q1), "=&v"(q2), "=&v"(q3),
      "=&v"(q4), "=&v"(q5), "=&v"(q6), "=&v"(q7)
    : [a] "v"(p)
    : "memory");
}

// ---------------- Phase 0a: X f32 -> bf16 (layout preserved [m][k]) ------
__global__ __launch_bounds__(256) void preconv_x(
    const float* __restrict__ X, unsigned short* __restrict__ Xbf)
{
  const size_t base = ((size_t)blockIdx.x*256 + threadIdx.x) * 8;
  const float4 v0 = *reinterpret_cast<const float4*>(&X[base]);
  const float4 v1 = *reinterpret_cast<const float4*>(&X[base + 4]);
  short8 t;
  t[0]=(short)bf16bits(v0.x); t[1]=(short)bf16bits(v0.y);
  t[2]=(short)bf16bits(v0.z); t[3]=(short)bf16bits(v0.w);
  t[4]=(short)bf16bits(v1.x); t[5]=(short)bf16bits(v1.y);
  t[6]=(short)bf16bits(v1.z); t[7]=(short)bf16bits(v1.w);
  *reinterpret_cast<short8*>(&Xbf[base]) = t;
}

// ---------------- Phase 0b: K [k][n] f32 -> KbfT [n][k] bf16 -------------
__global__ __launch_bounds__(256) void transp_k(
    const float* __restrict__ Kf, const float* __restrict__ Kb,
    unsigned short* __restrict__ KbfT)   // [dir][4096][512]
{
  __shared__ float tile[64][68];
  const int k0 = blockIdx.x * 64;
  const int n0 = blockIdx.y * 64;
  const int dir = blockIdx.z;
  const float* Km = dir ? Kb : Kf;
  const int tid = threadIdx.x;

  #pragma unroll
  for (int i = 0; i < 4; ++i) {
    const int kr = (tid >> 4) + i*16;
    const int nc = (tid & 15) * 4;
    const float4 v = *reinterpret_cast<const float4*>(&Km[(size_t)(k0+kr)*G4_ + n0 + nc]);
    tile[kr][nc+0] = v.x; tile[kr][nc+1] = v.y;
    tile[kr][nc+2] = v.z; tile[kr][nc+3] = v.w;
  }
  __syncthreads();
  const int n  = tid >> 2;
  const int kc = (tid & 3) * 16;
  short8 a, b;
  #pragma unroll
  for (int j = 0; j < 8; ++j) a[j] = (short)bf16bits(tile[kc + j][n]);
  #pragma unroll
  for (int j = 0; j < 8; ++j) b[j] = (short)bf16bits(tile[kc + 8 + j][n]);
  unsigned short* out = &KbfT[((size_t)dir*G4_ + n0 + n)*F_ + k0 + kc];
  *reinterpret_cast<short8*>(out)     = a;
  *reinterpret_cast<short8*>(out + 8) = b;
}

// ---------------- Phase 1: xw = Xbf @ KbfT^T + b (LDS-free MFMA) ---------
__global__ __launch_bounds__(256) void gemm_xw(
    const unsigned short* __restrict__ Xbf,    // [6400][512]
    const unsigned short* __restrict__ KbfT,   // [dir][4096][512]
    const float* __restrict__ Bf, const float* __restrict__ Bb,
    __half* __restrict__ xwf, __half* __restrict__ xwb)
{
  const int dir = blockIdx.z;
  const float* bias = dir ? Bb : Bf;
  __half* outp      = dir ? xwb : xwf;
  const unsigned short* Kt = KbfT + (size_t)dir*G4_*F_;
  const int m0 = blockIdx.x * 128;
  const int n0 = blockIdx.y * 128;
  const int tid = threadIdx.x, wid = tid >> 6, lane = tid & 63;
  const int wm = wid >> 1, wn = wid & 1;
  const int arow = lane & 15, kgrp = lane >> 4;

  const unsigned short* ap = &Xbf[(size_t)(m0 + wm*64 + arow)*F_ + kgrp*8];
  const unsigned short* bp = &Kt [(size_t)(n0 + wn*64 + arow)*F_ + kgrp*8];

  f32x4 acc[4][4];
  #pragma unroll
  for (int i = 0; i < 4; ++i)
    #pragma unroll
    for (int j = 0; j < 4; ++j)
      acc[i][j] = (f32x4){0.f,0.f,0.f,0.f};

  #pragma unroll 2
  for (int kk = 0; kk < 16; ++kk) {
    const int ko = kk*32;
    short8 af[4], bf4[4];
    #pragma unroll
    for (int t = 0; t < 4; ++t) {
      af[t]  = *reinterpret_cast<const short8*>(ap + (size_t)t*16*F_ + ko);
      bf4[t] = *reinterpret_cast<const short8*>(bp + (size_t)t*16*F_ + ko);
    }
    #pragma unroll
    for (int mt = 0; mt < 4; ++mt)
      #pragma unroll
      for (int nt = 0; nt < 4; ++nt)
        acc[mt][nt] = __builtin_amdgcn_mfma_f32_16x16x32_bf16(af[mt], bf4[nt], acc[mt][nt], 0, 0, 0);
  }
  #pragma unroll
  for (int mt = 0; mt < 4; ++mt) {
    #pragma unroll
    for (int nt = 0; nt < 4; ++nt) {
      const int n = n0 + wn*64 + nt*16 + arow;
      const float bv = bias[n];
      #pragma unroll
      for (int r = 0; r < 4; ++r) {
        const int m = m0 + wm*64 + mt*16 + kgrp*4 + r;
        outp[(size_t)m*G4_ + n] = __float2half_rn(acc[mt][nt][r] + bv);
      }
    }
  }
}

// ---------------- Phase 2: persistent bidirectional LSTM (MFMA) ----------
// 64 WGs (32/dir), each owns 32 u-cols = 128 gate-cols; all 64 B-fragments
// in registers. h: packed tagged dwords (bit0 tag, ((s>>1)&1)^1).
// ACQUIRE = DATA-POLL: the tag-validated full fragment load IS the spin
// (one RT merged; r6 structure at 1/4 WG count -> congestion tolerable).
__global__ __launch_bounds__(256, 1) void lstm_rec(
    const __half* __restrict__ xwf, const __half* __restrict__ xwb,
    const float* __restrict__ Rf, const float* __restrict__ Rb,
    const float* __restrict__ gammav, const float* __restrict__ betav,
    const float* __restrict__ mmean, const float* __restrict__ mvar,
    unsigned* __restrict__ hw2p,    // [par2][dir2][16][512] packed dwords
    float* __restrict__ outp)       // [16][400][2048] f32
{
  __shared__ unsigned short r_stage[32*1032];  // 66048 B (init only)
  __shared__ float z_s[4][16][132];            // 33792 B [wave][b][zc+pad]
  // total 99840 B -> 1 WG/CU

  const int wg  = blockIdx.x;
  const int dir = wg >> 5;
  const int u0  = (wg & 31) * 32;
  const __half* xw = dir ? xwb : xwf;
  const float*  R  = dir ? Rb  : Rf;
  const int tid  = threadIdx.x;
  const int wid  = tid >> 6;
  const int lane = tid & 63;
  const int arow = lane & 15;                  // batch row (MFMA)
  const int kgrp = lane >> 4;

  // ---- stage r in 4 rounds (gate j), land B-fragments in registers ----
  short8 rbf[8][8];
  #pragma unroll
  for (int j = 0; j < 4; ++j) {
    {
      const int c4l = (tid & 7) * 4;           // local col 0..31 (gate j)
      const int kb  = (tid >> 3) * 32;         // 32 k per thread
      const int gcol = j*U_ + u0 + c4l;
      for (int kk = 0; kk < 32; ++kk) {
        const float4 rv = *reinterpret_cast<const float4*>(&R[(size_t)(kb+kk)*G4_ + gcol]);
        r_stage[(c4l+0)*1032 + kb+kk] = (unsigned short)bf16bits(rv.x);
        r_stage[(c4l+1)*1032 + kb+kk] = (unsigned short)bf16bits(rv.y);
        r_stage[(c4l+2)*1032 + kb+kk] = (unsigned short)bf16bits(rv.z);
        r_stage[(c4l+3)*1032 + kb+kk] = (unsigned short)bf16bits(rv.w);
      }
    }
    __syncthreads();
    #pragma unroll
    for (int tt = 0; tt < 2; ++tt) {
      const int lc = tt*16 + arow;
      #pragma unroll
      for (int ks = 0; ks < 8; ++ks)
        rbf[2*j + tt][ks] = *reinterpret_cast<const short8*>(
            &r_stage[lc*1032 + wid*256 + ks*32 + kgrp*8]);
    }
    __syncthreads();
  }

  // reduce-thread mapping: uu = tid&31, batches b0 = tid>>5 and b0+8
  const int uu = tid & 31, b0 = tid >> 5, b1 = b0 + 8;
  float inv, add, cst0 = 0.f, cst1 = 0.f;
  {
    const int j = dir*U_ + u0 + uu;
    inv = gammav[j] * rsqrtf(mvar[j] + 1e-3f);
    add = betav[j] - mmean[j]*inv;
    if (!(uu & 1)) {                           // h(0)=0, parity 0, tag=1
      ast(&hw2p[(size_t)((0*2 + dir)*16 + b0)*512 + ((u0 + uu) >> 1)], 1u);
      ast(&hw2p[(size_t)((0*2 + dir)*16 + b1)*512 + ((u0 + uu) >> 1)], 1u);
    }
  }
  __syncthreads();

  const size_t hfrag_off = (size_t)arow*512 + wid*128 + kgrp*4;

  for (int s = 0; s < T_; ++s) {
    const int tin = dir ? (T_-1-s) : s;

    // xw prefetch: 2 batches x 4 gates (plain cached loads, pre-poll)
    float x0i, x0f, x0g, x0o, x1i, x1f, x1g, x1o;
    {
      const __half* xp0 = &xw[((size_t)b0*T_ + tin)*G4_ + u0 + uu];
      const __half* xp1 = &xw[((size_t)b1*T_ + tin)*G4_ + u0 + uu];
      x0i = __half2float(xp0[0]);    x0f = __half2float(xp0[1024]);
      x0g = __half2float(xp0[2048]); x0o = __half2float(xp0[3072]);
      x1i = __half2float(xp1[0]);    x1f = __half2float(xp1[1024]);
      x1g = __half2float(xp1[2048]); x1o = __half2float(xp1[3072]);
    }

    const unsigned eb = (((unsigned)s >> 1) & 1u) ^ 1u;   // expected tag bit
    const size_t pbase = (size_t)((s&1)*2 + dir)*8192;
    #define CKB(Q) (((Q.x ^ eb) | (Q.y ^ eb) | (Q.z ^ eb) | (Q.w ^ eb)) & 1u)

    // DATA-POLL acquire: full tag-validated fragment load IS the spin
    const unsigned* hgp = hw2p + pbase + hfrag_off;
    uint4 q0,q1,q2,q3,q4,q5,q6,q7;
    for (;;) {
      load_frag8(hgp, q0,q1,q2,q3,q4,q5,q6,q7);
      const unsigned mism = CKB(q0)|CKB(q1)|CKB(q2)|CKB(q3)
                          | CKB(q4)|CKB(q5)|CKB(q6)|CKB(q7);
      if (__all((int)(mism == 0u))) break;
      __builtin_amdgcn_s_sleep(2);
    }
    #undef CKB
    __builtin_amdgcn_sched_barrier(0);

    // MFMA: 8 k-fragments x 8 col-tiles (independent acc chains)
    f32x4 acc[8];
    #pragma unroll
    for (int t = 0; t < 8; ++t) acc[t] = (f32x4){0.f,0.f,0.f,0.f};
    #define FRAGK(Q, KS) { \
      const short8 a = *reinterpret_cast<const short8*>(&Q); \
      _Pragma("unroll") \
      for (int t = 0; t < 8; ++t) \
        acc[t] = __builtin_amdgcn_mfma_f32_16x16x32_bf16(a, rbf[t][KS], acc[t], 0, 0, 0); }
    FRAGK(q0, 0) FRAGK(q1, 1) FRAGK(q2, 2) FRAGK(q3, 3)
    FRAGK(q4, 4) FRAGK(q5, 5) FRAGK(q6, 6) FRAGK(q7, 7)
    #undef FRAGK

    // z partials: D col=lane&15, row=kgrp*4+r (batch); zc = t*16 + col
    {
      const int col = lane & 15, rbase = kgrp*4;
      #pragma unroll
      for (int t = 0; t < 8; ++t)
        #pragma unroll
        for (int r = 0; r < 4; ++r)
          z_s[wid][rbase+r][t*16 + col] = acc[t][r];
    }
    __syncthreads();                           // barrier 1: z complete

    // split reduce: zc = gate*32 + uu
    float z0i = x0i, z0f = x0f, z0g = x0g, z0o = x0o;
    float z1i = x1i, z1f = x1f, z1g = x1g, z1o = x1o;
    #pragma unroll
    for (int w = 0; w < 4; ++w) {
      z0i += z_s[w][b0][uu];      z1i += z_s[w][b1][uu];
      z0f += z_s[w][b0][32 + uu]; z1f += z_s[w][b1][32 + uu];
      z0g += z_s[w][b0][64 + uu]; z1g += z_s[w][b1][64 + uu];
      z0o += z_s[w][b0][96 + uu]; z1o += z_s[w][b1][96 + uu];
    }
    __syncthreads();                           // barrier 2: z reads done

    {
      const float ig0 = sigm(z0i), fg0 = sigm(z0f), og0 = sigm(z0o);
      const float gg0 = tanh_f(z0g);
      cst0 = fg0*cst0 + ig0*gg0;
      const float hv0 = og0 * tanh_f(cst0);
      const float ig1 = sigm(z1i), fg1 = sigm(z1f), og1 = sigm(z1o);
      const float gg1 = tanh_f(z1g);
      cst1 = fg1*cst1 + ig1*gg1;
      const float hv1 = og1 * tanh_f(cst1);
      const unsigned hvb0 = bf16bits(hv0);
      const unsigned hvb1 = bf16bits(hv1);
      const unsigned hnb0 = (unsigned)__shfl_down((int)hvb0, 1);
      const unsigned hnb1 = (unsigned)__shfl_down((int)hvb1, 1);
      if (!(uu & 1)) {
        const unsigned sbit = (((unsigned)(s+1) >> 1) & 1u) ^ 1u;
        const unsigned d0 = ((hvb0 & ~1u) | sbit) | (hnb0 << 16);
        const unsigned d1 = ((hvb1 & ~1u) | sbit) | (hnb1 << 16);
        const size_t nb = (size_t)(((s+1)&1)*2 + dir)*8192;
        ast(&hw2p[nb + (size_t)b0*512 + ((u0 + uu) >> 1)], d0);
        ast(&hw2p[nb + (size_t)b1*512 + ((u0 + uu) >> 1)], d1);
      }
      outp[((size_t)b0*T_ + tin)*2048 + dir*U_ + u0 + uu] = hv0*inv + add;
      outp[((size_t)b1*T_ + tin)*2048 + dir*U_ + u0 + uu] = hv1*inv + add;
    }
  }
}

extern "C" void kernel_launch(void* const* d_in, const int* in_sizes, int n_in,
                              void* d_out, int out_size, void* d_ws, size_t ws_size,
                              hipStream_t stream)
{
  const float* x  = (const float*)d_in[0];
  const float* kf = (const float*)d_in[1];
  const float* rf = (const float*)d_in[2];
  const float* bf = (const float*)d_in[3];
  const float* kb = (const float*)d_in[4];
  const float* rb = (const float*)d_in[5];
  const float* bb = (const float*)d_in[6];
  const float* ga = (const float*)d_in[7];
  const float* be = (const float*)d_in[8];
  const float* mm = (const float*)d_in[9];
  const float* mv = (const float*)d_in[10];
  float* outp = (float*)d_out;

  // ws: [hw2p 256KB][Xbf 6.55MB][KbfT 8.39MB][xwf f16][xwb f16]
  unsigned* hw2p       = (unsigned*)d_ws;
  unsigned short* Xbf  = (unsigned short*)((char*)d_ws + 262144);
  unsigned short* KbfT = (unsigned short*)((char*)d_ws + 262144 + (size_t)6400*F_*2);
  __half* xwf          = (__half*)((char*)d_ws + 262144 + (size_t)6400*F_*2
                                   + (size_t)2*G4_*F_*2);
  __half* xwb          = xwf + (size_t)6400*G4_;

  hipMemsetAsync(hw2p, 0, 262144, stream);
  preconv_x<<<dim3(1600), dim3(256), 0, stream>>>(x, Xbf);
  transp_k<<<dim3(8, 64, 2), dim3(256), 0, stream>>>(kf, kb, KbfT);
  gemm_xw<<<dim3(50, 32, 2), dim3(256), 0, stream>>>(Xbf, KbfT, bf, bb, xwf, xwb);
  lstm_rec<<<dim3(64), dim3(256), 0, stream>>>(xwf, xwb, rf, rb, ga, be, mm, mv,
                                               hw2p, outp);
}

// Round 19
// 1612.253 us; speedup vs baseline: 1.0342x; 1.0342x over previous
//
#include <hip/hip_runtime.h>
#include <hip/hip_fp16.h>

#define B_  16
#define T_  400
#define F_  512
#define U_  1024
#define G4_ 4096

typedef __attribute__((ext_vector_type(8))) short short8;
typedef __attribute__((ext_vector_type(4))) float f32x4;

__device__ __forceinline__ unsigned bf16bits(float f) {
  unsigned u = __float_as_uint(f);
  return (u + 0x7fffu + ((u >> 16) & 1u)) >> 16;   // RNE f32->bf16
}
__device__ __forceinline__ float sigm(float x)   { return 1.f/(1.f + __expf(-x)); }
__device__ __forceinline__ float tanh_f(float x) { return 2.f/(1.f + __expf(-2.f*x)) - 1.f; }

__device__ __forceinline__ void ast(unsigned* p, unsigned v) {
  __hip_atomic_store(p, v, __ATOMIC_RELAXED, __HIP_MEMORY_SCOPE_AGENT);
}

// HARDENED coherent loads (rule #18-safe): waitcnt fused with the loads.
__device__ __forceinline__ void ald4x2_wait(const unsigned* p0, const unsigned* p1,
                                            uint4& t0, uint4& t1) {
  asm volatile("global_load_dwordx4 %0, %[a], off sc0 sc1\n\t"
               "global_load_dwordx4 %1, %[b], off sc0 sc1\n\t"
               "s_waitcnt vmcnt(0)"
               : "=&v"(t0), "=&v"(t1) : [a] "v"(p0), [b] "v"(p1) : "memory");
}
__device__ __forceinline__ void load_frag8(const unsigned* p,
    uint4& q0, uint4& q1, uint4& q2, uint4& q3,
    uint4& q4, uint4& q5, uint4& q6, uint4& q7) {
  asm volatile(
    "global_load_dwordx4 %0, %[a], off sc0 sc1\n\t"
    "global_load_dwordx4 %1, %[a], off offset:64 sc0 sc1\n\t"
    "global_load_dwordx4 %2, %[a], off offset:128 sc0 sc1\n\t"
    "global_load_dwordx4 %3, %[a], off offset:192 sc0 sc1\n\t"
    "global_load_dwordx4 %4, %[a], off offset:256 sc0 sc1\n\t"
    "global_load_dwordx4 %5, %[a], off offset:320 sc0 sc1\n\t"
    "global_load_dwordx4 %6, %[a], off offset:384 sc0 sc1\n\t"
    "global_load_dwordx4 %7, %[a], off offset:448 sc0 sc1\n\t"
    "s_waitcnt vmcnt(0)"
    : "=&v"(q0), "=&v"(q1), "=&v"(q2), "=&v"(q3),
      "=&v"(q4), "=&v"(q5), "=&v"(q6), "=&v"(q7)
    : [a] "v"(p)
    : "memory");
}

// ---------------- Phase 0a: X f32 -> bf16 (layout preserved [m][k]) ------
__global__ __launch_bounds__(256) void preconv_x(
    const float* __restrict__ X, unsigned short* __restrict__ Xbf)
{
  const size_t base = ((size_t)blockIdx.x*256 + threadIdx.x) * 8;
  const float4 v0 = *reinterpret_cast<const float4*>(&X[base]);
  const float4 v1 = *reinterpret_cast<const float4*>(&X[base + 4]);
  short8 t;
  t[0]=(short)bf16bits(v0.x); t[1]=(short)bf16bits(v0.y);
  t[2]=(short)bf16bits(v0.z); t[3]=(short)bf16bits(v0.w);
  t[4]=(short)bf16bits(v1.x); t[5]=(short)bf16bits(v1.y);
  t[6]=(short)bf16bits(v1.z); t[7]=(short)bf16bits(v1.w);
  *reinterpret_cast<short8*>(&Xbf[base]) = t;
}

// ---------------- Phase 0b: K [k][n] f32 -> KbfT [n][k] bf16 -------------
__global__ __launch_bounds__(256) void transp_k(
    const float* __restrict__ Kf, const float* __restrict__ Kb,
    unsigned short* __restrict__ KbfT)   // [dir][4096][512]
{
  __shared__ float tile[64][68];
  const int k0 = blockIdx.x * 64;
  const int n0 = blockIdx.y * 64;
  const int dir = blockIdx.z;
  const float* Km = dir ? Kb : Kf;
  const int tid = threadIdx.x;

  #pragma unroll
  for (int i = 0; i < 4; ++i) {
    const int kr = (tid >> 4) + i*16;
    const int nc = (tid & 15) * 4;
    const float4 v = *reinterpret_cast<const float4*>(&Km[(size_t)(k0+kr)*G4_ + n0 + nc]);
    tile[kr][nc+0] = v.x; tile[kr][nc+1] = v.y;
    tile[kr][nc+2] = v.z; tile[kr][nc+3] = v.w;
  }
  __syncthreads();
  const int n  = tid >> 2;
  const int kc = (tid & 3) * 16;
  short8 a, b;
  #pragma unroll
  for (int j = 0; j < 8; ++j) a[j] = (short)bf16bits(tile[kc + j][n]);
  #pragma unroll
  for (int j = 0; j < 8; ++j) b[j] = (short)bf16bits(tile[kc + 8 + j][n]);
  unsigned short* out = &KbfT[((size_t)dir*G4_ + n0 + n)*F_ + k0 + kc];
  *reinterpret_cast<short8*>(out)     = a;
  *reinterpret_cast<short8*>(out + 8) = b;
}

// ---------------- Phase 1: xw = Xbf @ KbfT^T + b (LDS-free MFMA) ---------
__global__ __launch_bounds__(256) void gemm_xw(
    const unsigned short* __restrict__ Xbf,    // [6400][512]
    const unsigned short* __restrict__ KbfT,   // [dir][4096][512]
    const float* __restrict__ Bf, const float* __restrict__ Bb,
    __half* __restrict__ xwf, __half* __restrict__ xwb)
{
  const int dir = blockIdx.z;
  const float* bias = dir ? Bb : Bf;
  __half* outp      = dir ? xwb : xwf;
  const unsigned short* Kt = KbfT + (size_t)dir*G4_*F_;
  const int m0 = blockIdx.x * 128;
  const int n0 = blockIdx.y * 128;
  const int tid = threadIdx.x, wid = tid >> 6, lane = tid & 63;
  const int wm = wid >> 1, wn = wid & 1;
  const int arow = lane & 15, kgrp = lane >> 4;

  const unsigned short* ap = &Xbf[(size_t)(m0 + wm*64 + arow)*F_ + kgrp*8];
  const unsigned short* bp = &Kt [(size_t)(n0 + wn*64 + arow)*F_ + kgrp*8];

  f32x4 acc[4][4];
  #pragma unroll
  for (int i = 0; i < 4; ++i)
    #pragma unroll
    for (int j = 0; j < 4; ++j)
      acc[i][j] = (f32x4){0.f,0.f,0.f,0.f};

  #pragma unroll 2
  for (int kk = 0; kk < 16; ++kk) {
    const int ko = kk*32;
    short8 af[4], bf4[4];
    #pragma unroll
    for (int t = 0; t < 4; ++t) {
      af[t]  = *reinterpret_cast<const short8*>(ap + (size_t)t*16*F_ + ko);
      bf4[t] = *reinterpret_cast<const short8*>(bp + (size_t)t*16*F_ + ko);
    }
    #pragma unroll
    for (int mt = 0; mt < 4; ++mt)
      #pragma unroll
      for (int nt = 0; nt < 4; ++nt)
        acc[mt][nt] = __builtin_amdgcn_mfma_f32_16x16x32_bf16(af[mt], bf4[nt], acc[mt][nt], 0, 0, 0);
  }
  #pragma unroll
  for (int mt = 0; mt < 4; ++mt) {
    #pragma unroll
    for (int nt = 0; nt < 4; ++nt) {
      const int n = n0 + wn*64 + nt*16 + arow;
      const float bv = bias[n];
      #pragma unroll
      for (int r = 0; r < 4; ++r) {
        const int m = m0 + wm*64 + mt*16 + kgrp*4 + r;
        outp[(size_t)m*G4_ + n] = __float2half_rn(acc[mt][nt][r] + bv);
      }
    }
  }
}

// ---------------- Phase 2: persistent bidirectional LSTM (MFMA) ----------
// EXACT round-17 best kernel. 64 WGs (32/dir), 32 u-cols/WG, all 64
// B-fragments in registers; packed tagged h dwords; two-tier wait-until-
// fresh acquire (cheap 2-dwordx4 sample spin -> validated full load).
__global__ __launch_bounds__(256, 1) void lstm_rec(
    const __half* __restrict__ xwf, const __half* __restrict__ xwb,
    const float* __restrict__ Rf, const float* __restrict__ Rb,
    const float* __restrict__ gammav, const float* __restrict__ betav,
    const float* __restrict__ mmean, const float* __restrict__ mvar,
    unsigned* __restrict__ hw2p,    // [par2][dir2][16][512] packed dwords
    float* __restrict__ outp)       // [16][400][2048] f32
{
  __shared__ unsigned short r_stage[32*1032];  // 66048 B (init only)
  __shared__ float z_s[4][16][132];            // 33792 B [wave][b][zc+pad]
  // total 99840 B -> 1 WG/CU

  const int wg  = blockIdx.x;
  const int dir = wg >> 5;
  const int u0  = (wg & 31) * 32;
  const __half* xw = dir ? xwb : xwf;
  const float*  R  = dir ? Rb  : Rf;
  const int tid  = threadIdx.x;
  const int wid  = tid >> 6;
  const int lane = tid & 63;
  const int arow = lane & 15;                  // batch row (MFMA)
  const int kgrp = lane >> 4;

  // ---- stage r in 4 rounds (gate j), land B-fragments in registers ----
  short8 rbf[8][8];
  #pragma unroll
  for (int j = 0; j < 4; ++j) {
    {
      const int c4l = (tid & 7) * 4;           // local col 0..31 (gate j)
      const int kb  = (tid >> 3) * 32;         // 32 k per thread
      const int gcol = j*U_ + u0 + c4l;
      for (int kk = 0; kk < 32; ++kk) {
        const float4 rv = *reinterpret_cast<const float4*>(&R[(size_t)(kb+kk)*G4_ + gcol]);
        r_stage[(c4l+0)*1032 + kb+kk] = (unsigned short)bf16bits(rv.x);
        r_stage[(c4l+1)*1032 + kb+kk] = (unsigned short)bf16bits(rv.y);
        r_stage[(c4l+2)*1032 + kb+kk] = (unsigned short)bf16bits(rv.z);
        r_stage[(c4l+3)*1032 + kb+kk] = (unsigned short)bf16bits(rv.w);
      }
    }
    __syncthreads();
    #pragma unroll
    for (int tt = 0; tt < 2; ++tt) {
      const int lc = tt*16 + arow;             // local col in stage
      #pragma unroll
      for (int ks = 0; ks < 8; ++ks)
        rbf[2*j + tt][ks] = *reinterpret_cast<const short8*>(
            &r_stage[lc*1032 + wid*256 + ks*32 + kgrp*8]);
    }
    __syncthreads();
  }

  // reduce-thread mapping: uu = tid&31, batches b0 = tid>>5 and b0+8
  const int uu = tid & 31, b0 = tid >> 5, b1 = b0 + 8;
  float inv, add, cst0 = 0.f, cst1 = 0.f;
  {
    const int j = dir*U_ + u0 + uu;
    inv = gammav[j] * rsqrtf(mvar[j] + 1e-3f);
    add = betav[j] - mmean[j]*inv;
    if (!(uu & 1)) {                           // h(0)=0, parity 0, tag=1
      ast(&hw2p[(size_t)((0*2 + dir)*16 + b0)*512 + ((u0 + uu) >> 1)], 1u);
      ast(&hw2p[(size_t)((0*2 + dir)*16 + b1)*512 + ((u0 + uu) >> 1)], 1u);
    }
  }
  __syncthreads();

  const size_t hfrag_off = (size_t)arow*512 + wid*128 + kgrp*4;
  // sample: producer p = lane&7 of this quarter, batches (lane>>3) and +8
  const size_t samp_off0 = (size_t)(lane >> 3)*512       + wid*128 + (lane & 7)*16;
  const size_t samp_off1 = (size_t)((lane >> 3) + 8)*512 + wid*128 + (lane & 7)*16;

  for (int s = 0; s < T_; ++s) {
    const int tin = dir ? (T_-1-s) : s;

    // xw prefetch: 2 batches x 4 gates (plain cached loads, pre-poll)
    float x0i, x0f, x0g, x0o, x1i, x1f, x1g, x1o;
    {
      const __half* xp0 = &xw[((size_t)b0*T_ + tin)*G4_ + u0 + uu];
      const __half* xp1 = &xw[((size_t)b1*T_ + tin)*G4_ + u0 + uu];
      x0i = __half2float(xp0[0]);    x0f = __half2float(xp0[1024]);
      x0g = __half2float(xp0[2048]); x0o = __half2float(xp0[3072]);
      x1i = __half2float(xp1[0]);    x1f = __half2float(xp1[1024]);
      x1g = __half2float(xp1[2048]); x1o = __half2float(xp1[3072]);
    }

    const unsigned eb = (((unsigned)s >> 1) & 1u) ^ 1u;   // expected tag bit
    const size_t pbase = (size_t)((s&1)*2 + dir)*8192;
    #define CKB(Q) (((Q.x ^ eb) | (Q.y ^ eb) | (Q.z ^ eb) | (Q.w ^ eb)) & 1u)

    // cheap sample poll: 2 dwordx4/lane covers 8 producers x 16 batches
    {
      const unsigned* sp0 = hw2p + pbase + samp_off0;
      const unsigned* sp1 = hw2p + pbase + samp_off1;
      for (;;) {
        uint4 t0, t1;
        ald4x2_wait(sp0, sp1, t0, t1);
        if (__all((int)((CKB(t0) | CKB(t1)) == 0u))) break;
        __builtin_amdgcn_s_sleep(1);
      }
    }

    // full fragment load (8 x dwordx4 = 128B/lane), tag-validated
    const unsigned* hgp = hw2p + pbase + hfrag_off;
    uint4 q0,q1,q2,q3,q4,q5,q6,q7;
    for (;;) {
      load_frag8(hgp, q0,q1,q2,q3,q4,q5,q6,q7);
      const unsigned mism = CKB(q0)|CKB(q1)|CKB(q2)|CKB(q3)
                          | CKB(q4)|CKB(q5)|CKB(q6)|CKB(q7);
      if (__all((int)(mism == 0u))) break;
      __builtin_amdgcn_s_sleep(1);
    }
    #undef CKB
    __builtin_amdgcn_sched_barrier(0);

    // MFMA: 8 k-fragments x 8 col-tiles (independent acc chains)
    f32x4 acc[8];
    #pragma unroll
    for (int t = 0; t < 8; ++t) acc[t] = (f32x4){0.f,0.f,0.f,0.f};
    #define FRAGK(Q, KS) { \
      const short8 a = *reinterpret_cast<const short8*>(&Q); \
      _Pragma("unroll") \
      for (int t = 0; t < 8; ++t) \
        acc[t] = __builtin_amdgcn_mfma_f32_16x16x32_bf16(a, rbf[t][KS], acc[t], 0, 0, 0); }
    FRAGK(q0, 0) FRAGK(q1, 1) FRAGK(q2, 2) FRAGK(q3, 3)
    FRAGK(q4, 4) FRAGK(q5, 5) FRAGK(q6, 6) FRAGK(q7, 7)
    #undef FRAGK

    // z partials: D col=lane&15, row=kgrp*4+r (batch); zc = t*16 + col
    {
      const int col = lane & 15, rbase = kgrp*4;
      #pragma unroll
      for (int t = 0; t < 8; ++t)
        #pragma unroll
        for (int r = 0; r < 4; ++r)
          z_s[wid][rbase+r][t*16 + col] = acc[t][r];
    }
    __syncthreads();                           // barrier 1: z complete

    // split reduce: zc = gate*32 + uu
    float z0i = x0i, z0f = x0f, z0g = x0g, z0o = x0o;
    float z1i = x1i, z1f = x1f, z1g = x1g, z1o = x1o;
    #pragma unroll
    for (int w = 0; w < 4; ++w) {
      z0i += z_s[w][b0][uu];      z1i += z_s[w][b1][uu];
      z0f += z_s[w][b0][32 + uu]; z1f += z_s[w][b1][32 + uu];
      z0g += z_s[w][b0][64 + uu]; z1g += z_s[w][b1][64 + uu];
      z0o += z_s[w][b0][96 + uu]; z1o += z_s[w][b1][96 + uu];
    }
    __syncthreads();                           // barrier 2: z reads done

    {
      const float ig0 = sigm(z0i), fg0 = sigm(z0f), og0 = sigm(z0o);
      const float gg0 = tanh_f(z0g);
      cst0 = fg0*cst0 + ig0*gg0;
      const float hv0 = og0 * tanh_f(cst0);
      const float ig1 = sigm(z1i), fg1 = sigm(z1f), og1 = sigm(z1o);
      const float gg1 = tanh_f(z1g);
      cst1 = fg1*cst1 + ig1*gg1;
      const float hv1 = og1 * tanh_f(cst1);
      const unsigned hvb0 = bf16bits(hv0);
      const unsigned hvb1 = bf16bits(hv1);
      const unsigned hnb0 = (unsigned)__shfl_down((int)hvb0, 1);
      const unsigned hnb1 = (unsigned)__shfl_down((int)hvb1, 1);
      if (!(uu & 1)) {
        const unsigned sbit = (((unsigned)(s+1) >> 1) & 1u) ^ 1u;
        const unsigned d0 = ((hvb0 & ~1u) | sbit) | (hnb0 << 16);
        const unsigned d1 = ((hvb1 & ~1u) | sbit) | (hnb1 << 16);
        const size_t nb = (size_t)(((s+1)&1)*2 + dir)*8192;
        ast(&hw2p[nb + (size_t)b0*512 + ((u0 + uu) >> 1)], d0);
        ast(&hw2p[nb + (size_t)b1*512 + ((u0 + uu) >> 1)], d1);
      }
      outp[((size_t)b0*T_ + tin)*2048 + dir*U_ + u0 + uu] = hv0*inv + add;
      outp[((size_t)b1*T_ + tin)*2048 + dir*U_ + u0 + uu] = hv1*inv + add;
    }
  }
}

extern "C" void kernel_launch(void* const* d_in, const int* in_sizes, int n_in,
                              void* d_out, int out_size, void* d_ws, size_t ws_size,
                              hipStream_t stream)
{
  const float* x  = (const float*)d_in[0];
  const float* kf = (const float*)d_in[1];
  const float* rf = (const float*)d_in[2];
  const float* bf = (const float*)d_in[3];
  const float* kb = (const float*)d_in[4];
  const float* rb = (const float*)d_in[5];
  const float* bb = (const float*)d_in[6];
  const float* ga = (const float*)d_in[7];
  const float* be = (const float*)d_in[8];
  const float* mm = (const float*)d_in[9];
  const float* mv = (const float*)d_in[10];
  float* outp = (float*)d_out;

  // ws: [hw2p 256KB][Xbf 6.55MB][KbfT 8.39MB][xwf f16][xwb f16]
  unsigned* hw2p       = (unsigned*)d_ws;
  unsigned short* Xbf  = (unsigned short*)((char*)d_ws + 262144);
  unsigned short* KbfT = (unsigned short*)((char*)d_ws + 262144 + (size_t)6400*F_*2);
  __half* xwf          = (__half*)((char*)d_ws + 262144 + (size_t)6400*F_*2
                                   + (size_t)2*G4_*F_*2);
  __half* xwb          = xwf + (size_t)6400*G4_;

  hipMemsetAsync(hw2p, 0, 262144, stream);
  preconv_x<<<dim3(1600), dim3(256), 0, stream>>>(x, Xbf);
  transp_k<<<dim3(8, 64, 2), dim3(256), 0, stream>>>(kf, kb, KbfT);
  gemm_xw<<<dim3(50, 32, 2), dim3(256), 0, stream>>>(Xbf, KbfT, bf, bb, xwf, xwb);
  lstm_rec<<<dim3(64), dim3(256), 0, stream>>>(xwf, xwb, rf, rb, ga, be, mm, mv,
                                               hw2p, outp);
}